// Round 6
// baseline (410.225 us; speedup 1.0000x reference)
//
#include <hip/hip_runtime.h>
#include <hip/hip_cooperative_groups.h>
#include <hip/hip_bf16.h>
#include <stdint.h>
#include <math.h>

#define NODES 8192
#define EDGES 4096
#define DIM   128
#define HID   256
#define NHEADS 4

namespace cg = cooperative_groups;

using bf8   = __attribute__((ext_vector_type(8))) short;
using f32x4 = __attribute__((ext_vector_type(4))) float;
using i32x4 = __attribute__((ext_vector_type(4))) int;
using s16x4 = __attribute__((ext_vector_type(4))) short;

__device__ __forceinline__ short f2bf(float f) {
    uint32_t u = __float_as_uint(f);
    u += 0x7fffu + ((u >> 16) & 1u);   // RNE
    return (short)(u >> 16);
}
__device__ __forceinline__ float bf2f(short s) {
    return __uint_as_float(((uint32_t)(unsigned short)s) << 16);
}
// order-preserving float<->uint key for atomic min/max
__device__ __forceinline__ unsigned fkey(float f) {
    unsigned u = __float_as_uint(f);
    return (u & 0x80000000u) ? ~u : (u | 0x80000000u);
}
__device__ __forceinline__ float fdec(unsigned k) {
    unsigned u = (k & 0x80000000u) ? (k & 0x7fffffffu) : ~k;
    return __uint_as_float(u);
}

// Fragment-swizzled operand layout for 16x16x32 MFMA:
//   buf[(tile16 * 128 + chunk32) * 512 + lane * 8 .. +7]  (shorts)
// lane = q*16 + r holds elems [row/col = tile*16 + r][k = chunk*32 + q*8 + j].

// ============ k_init: incidence->swizzled bf16 (no LDS, no barriers) + rowsum,
//              ef->swizzled bf16, x->bf16, fused weights/vectors, amin/amax init ============
__global__ __launch_bounds__(256) void k_init(
        const float* __restrict__ inc, short* __restrict__ incB,
        const float* __restrict__ ef, short* __restrict__ efB,
        const float* __restrict__ xf, short* __restrict__ xb,
        const float* __restrict__ Wn, const float* __restrict__ We, const float* __restrict__ Wo,
        const float* __restrict__ Wa, const float* __restrict__ bn, const float* __restrict__ be,
        const float* __restrict__ ba, const float* __restrict__ bo,
        short* __restrict__ A1T, short* __restrict__ A2T,
        float* __restrict__ v1, float* __restrict__ v2,
        float* __restrict__ u1, float* __restrict__ u2, float* __restrict__ cc,
        float* __restrict__ rs, float* __restrict__ idg,
        unsigned* __restrict__ amin, unsigned* __restrict__ amax) {
    __shared__ __align__(16) char smem[17408];
    int b = blockIdx.x, t = threadIdx.x;

    // ---- (1) blocks 0..127: build swizzled efB from ef [4096][128] (LDS transpose, 2 barriers) ----
    if (b < 128) {
        float (*lb)[132] = (float(*)[132])smem;
        int k0 = b * 32;
#pragma unroll
        for (int i = 0; i < 4; ++i) {
            int idx4 = t + i * 256;
            int kk = idx4 >> 5, nq = idx4 & 31;
            f32x4 v = *(const f32x4*)&ef[(size_t)(k0 + kk) * DIM + nq * 4];
            lb[kk][nq * 4 + 0] = v[0]; lb[kk][nq * 4 + 1] = v[1];
            lb[kk][nq * 4 + 2] = v[2]; lb[kk][nq * 4 + 3] = v[3];
        }
        __syncthreads();
#pragma unroll
        for (int i = 0; i < 2; ++i) {
            int o = t + i * 256;
            int nt = o >> 6, lane = o & 63, nr = lane & 15, qq = lane >> 4;
            bf8 pk;
#pragma unroll
            for (int j = 0; j < 8; ++j) pk[j] = f2bf(lb[qq * 8 + j][nt * 16 + nr]);
            *(bf8*)&efB[((size_t)nt * 128 + b) * 512 + lane * 8] = pk;
        }
        __syncthreads();
    }

    // ---- (2) all blocks: incidence 16-row tile b -> swizzled bf16 + rowsum; pure register path ----
    {
        const int row = t >> 4, koff = t & 15;
        const float* ip = inc + (size_t)(b * 16 + row) * EDGES + koff * 8;
        short* ob = incB + (size_t)b * 65536;   // tile b: 128 chunks * 512 shorts
        const int obase = (koff >> 2) * 512 + ((koff & 3) * 16 + row) * 8;
        float rsacc = 0.f;
#pragma unroll 4
        for (int sc = 0; sc < 32; ++sc) {
            f32x4 v0 = *(const f32x4*)(ip + sc * 128);
            f32x4 v1v = *(const f32x4*)(ip + sc * 128 + 4);
            bf8 pk;
#pragma unroll
            for (int j = 0; j < 4; ++j) {
                pk[j] = f2bf(v0[j]); pk[4 + j] = f2bf(v1v[j]);
                rsacc += v0[j] + v1v[j];
            }
            *(bf8*)&ob[(size_t)(sc * 4) * 512 + obase] = pk;
        }
        rsacc += __shfl_xor(rsacc, 1); rsacc += __shfl_xor(rsacc, 2);
        rsacc += __shfl_xor(rsacc, 4); rsacc += __shfl_xor(rsacc, 8);
        if (koff == 0) {
            rs[b * 16 + row] = rsacc;
            idg[b * 16 + row] = 1.f / (rsacc + 1e-8f);
        }
    }

    // ---- (3) node_features f32 -> bf16 ----
#pragma unroll
    for (int i = 0; i < 2; ++i) {
        int idx = b * 256 + t + i * 131072;
        f32x4 v = *((const f32x4*)xf + idx);
        s16x4 o;
#pragma unroll
        for (int j = 0; j < 4; ++j) o[j] = f2bf(v[j]);
        *((s16x4*)xb + idx) = o;
    }
    // ---- (4) amin/amax init (4 heads x 128) ----
    if (b == 511) {
#pragma unroll
        for (int i = 0; i < 2; ++i) {
            int u = t + i * 256;
            amin[u] = 0xFFFFFFFFu;
            amax[u] = 0u;
        }
    }

    // ---- (5) blocks 128..383: fused weights A1T=(Wn@Wo)^T, A2T=(We@Wo)^T ----
    if (b >= 128 && b < 384) {
        float (*lw)[128][17] = (float(*)[128][17])smem;
        int bb = b - 128;
        int h = bb >> 6, jj = bb & 63;
        int mat = t >> 7, k = t & 127;
        const float* WoH = Wo + (size_t)h * HID * DIM;
        float acc0 = 0.f, acc1 = 0.f;
        for (int mc = 0; mc < 16; ++mc) {
            __syncthreads();
#pragma unroll
            for (int i = 0; i < 4; ++i) {
                int u = t + i * 256;
                int m_ = u >> 9, kk2 = (u >> 2) & 127, qd = u & 3;
                const float* src = (m_ ? We : Wn) + (size_t)h * DIM * HID + (size_t)kk2 * HID + mc * 16 + qd * 4;
                f32x4 val = *(const f32x4*)src;
#pragma unroll
                for (int j2 = 0; j2 < 4; ++j2) lw[m_][kk2][qd * 4 + j2] = val[j2];
            }
            __syncthreads();
#pragma unroll
            for (int mm = 0; mm < 16; ++mm) {
                float a = lw[mat][k][mm];
                int m = mc * 16 + mm;
                acc0 += a * WoH[(size_t)m * DIM + jj];
                acc1 += a * WoH[(size_t)m * DIM + jj + 64];
            }
        }
        short* dst = mat ? A2T : A1T;
        dst[(size_t)h * DIM * DIM + (size_t)jj * DIM + k] = f2bf(acc0);
        dst[(size_t)h * DIM * DIM + (size_t)(jj + 64) * DIM + k] = f2bf(acc1);
    } else if (b >= 384 && b < 388) {
        // ---- (6) fused vectors for head h ----
        float (*lw)[128][17] = (float(*)[128][17])smem;
        int h = b - 384;
        int mat = t >> 7, k = t & 127;
        const float* wa = Wa + (size_t)h * HID;
        float acc = 0.f;
        for (int mc = 0; mc < 16; ++mc) {
            __syncthreads();
#pragma unroll
            for (int i = 0; i < 4; ++i) {
                int u = t + i * 256;
                int m_ = u >> 9, kk2 = (u >> 2) & 127, qd = u & 3;
                const float* src = (m_ ? We : Wn) + (size_t)h * DIM * HID + (size_t)kk2 * HID + mc * 16 + qd * 4;
                f32x4 val = *(const f32x4*)src;
#pragma unroll
                for (int j2 = 0; j2 < 4; ++j2) lw[m_][kk2][qd * 4 + j2] = val[j2];
            }
            __syncthreads();
#pragma unroll
            for (int mm = 0; mm < 16; ++mm) acc += lw[mat][k][mm] * wa[mc * 16 + mm];
        }
        (mat ? v2 : v1)[h * DIM + k] = acc;
        const float* bias = (mat ? be : bn) + (size_t)h * HID;
        const float* WoH = Wo + (size_t)h * HID * DIM;
        float ua = 0.f;
        for (int m = 0; m < HID; ++m) ua += bias[m] * WoH[(size_t)m * DIM + k];
        if (mat) u2[h * DIM + k] = ua;
        else     u1[h * DIM + k] = ua + bo[h * DIM + k];
        if (t < 64) {
            float c = 0.f;
#pragma unroll
            for (int j = 0; j < 4; ++j) { int m = t + j * 64; c += bn[(size_t)h * HID + m] * wa[m]; }
#pragma unroll
            for (int off = 1; off < 64; off <<= 1) c += __shfl_xor(c, off);
            if (t == 0) cc[h * 2 + 0] = c + ba[h];
        } else if (t < 128) {
            int l2 = t - 64;
            float c = 0.f;
#pragma unroll
            for (int j = 0; j < 4; ++j) { int m = l2 + j * 64; c += be[(size_t)h * HID + m] * wa[m]; }
#pragma unroll
            for (int off = 1; off < 64; off <<= 1) c += __shfl_xor(c, off);
            if (l2 == 0) cc[h * 2 + 1] = c;
        }
    }
}

// ============ k_mega (cooperative): P-tile GEMM (LDS-resident) + 4 fused heads + final out ============
// 256 blocks x 256 threads; block b owns rows [b*32, b*32+32) for the whole pipeline.
__global__ __launch_bounds__(256) void k_mega(
        const short* __restrict__ incB, const short* __restrict__ efB, const short* __restrict__ xb,
        const short* __restrict__ A1T, const short* __restrict__ A2T,
        const float* __restrict__ v1g, const float* __restrict__ v2g,
        const float* __restrict__ u1g, const float* __restrict__ u2g, const float* __restrict__ ccg,
        const float* __restrict__ rsg, const float* __restrict__ idgg,
        unsigned* __restrict__ amin, unsigned* __restrict__ amax,
        float* __restrict__ dout) {
    cg::grid_group grid = cg::this_grid();
    __shared__ float red[2][32][129];     // pgemm reduce; red[0] reused as f32 out-tile per head
    __shared__ short lp[32][136];         // P tile, bf16 (persists all heads)
    __shared__ short lx[32][136];         // x tile, bf16
    __shared__ float sv1[128], sv2[128], smn[128], srv[128];
    __shared__ float rsL[32], idL[32], coL[32];
    const int b = blockIdx.x, t = threadIdx.x;
    const int w = t >> 6, l = t & 63, q = l >> 4, lr = l & 15;

    // ---- phase P: P[b*32..+32][:] = inc-tile @ ef, straight into lp ----
    {
        const short* ap0 = incB + (((size_t)(b * 2)     * 128) + w * 32) * 512 + l * 8;
        const short* ap1 = incB + (((size_t)(b * 2 + 1) * 128) + w * 32) * 512 + l * 8;
        const short* bp  = efB + ((size_t)w * 32) * 512 + l * 8;
        f32x4 acc[2][8];
#pragma unroll
        for (int f = 0; f < 2; ++f)
#pragma unroll
            for (int cb = 0; cb < 8; ++cb) acc[f][cb] = (f32x4){0.f, 0.f, 0.f, 0.f};
        bf8 aA0, aA1, bA[8], aB0, aB1, bB[8];
        aA0 = *(const bf8*)ap0; aA1 = *(const bf8*)ap1;
#pragma unroll
        for (int cb = 0; cb < 8; ++cb) bA[cb] = *(const bf8*)(bp + (size_t)cb * 65536);
        for (int s = 0; s < 32; s += 2) {
            if (s + 1 < 32) {
                aB0 = *(const bf8*)(ap0 + (s + 1) * 512);
                aB1 = *(const bf8*)(ap1 + (s + 1) * 512);
#pragma unroll
                for (int cb = 0; cb < 8; ++cb) bB[cb] = *(const bf8*)(bp + (size_t)cb * 65536 + (s + 1) * 512);
            }
#pragma unroll
            for (int cb = 0; cb < 8; ++cb) {
                acc[0][cb] = __builtin_amdgcn_mfma_f32_16x16x32_bf16(aA0, bA[cb], acc[0][cb], 0, 0, 0);
                acc[1][cb] = __builtin_amdgcn_mfma_f32_16x16x32_bf16(aA1, bA[cb], acc[1][cb], 0, 0, 0);
            }
            if (s + 2 < 32) {
                aA0 = *(const bf8*)(ap0 + (s + 2) * 512);
                aA1 = *(const bf8*)(ap1 + (s + 2) * 512);
#pragma unroll
                for (int cb = 0; cb < 8; ++cb) bA[cb] = *(const bf8*)(bp + (size_t)cb * 65536 + (s + 2) * 512);
            }
#pragma unroll
            for (int cb = 0; cb < 8; ++cb) {
                acc[0][cb] = __builtin_amdgcn_mfma_f32_16x16x32_bf16(aB0, bB[cb], acc[0][cb], 0, 0, 0);
                acc[1][cb] = __builtin_amdgcn_mfma_f32_16x16x32_bf16(aB1, bB[cb], acc[1][cb], 0, 0, 0);
            }
        }
        if (w < 2) {
#pragma unroll
            for (int f = 0; f < 2; ++f)
#pragma unroll
                for (int cb = 0; cb < 8; ++cb)
#pragma unroll
                    for (int r = 0; r < 4; ++r)
                        red[w][f * 16 + q * 4 + r][cb * 16 + lr] = acc[f][cb][r];
        }
        __syncthreads();
        if (w >= 2) {
#pragma unroll
            for (int f = 0; f < 2; ++f)
#pragma unroll
                for (int cb = 0; cb < 8; ++cb)
#pragma unroll
                    for (int r = 0; r < 4; ++r)
                        red[w - 2][f * 16 + q * 4 + r][cb * 16 + lr] += acc[f][cb][r];
        }
        __syncthreads();
#pragma unroll
        for (int i = 0; i < 2; ++i) {
            int idx = t + i * 256;
            int row = idx >> 4, c = (idx & 15) * 8;
            bf8 pk;
#pragma unroll
            for (int j = 0; j < 8; ++j) pk[j] = f2bf(red[0][row][c + j] + red[1][row][c + j]);
            *(bf8*)&lp[row][c] = pk;
        }
    }
    if (t < 32) { rsL[t] = rsg[b * 32 + t]; idL[t] = idgg[b * 32 + t]; }
    __syncthreads();

    // ---- 4 heads, grid-synced ----
    for (int h = 0; h < NHEADS; ++h) {
        if (t < 128) { sv1[t] = v1g[h * 128 + t]; sv2[t] = v2g[h * 128 + t]; }
        const float c1 = ccg[h * 2], c2 = ccg[h * 2 + 1];
        const short* W1 = A1T + (size_t)h * DIM * DIM;
        const short* W2 = A2T + (size_t)h * DIM * DIM;
        bf8 b1f[2][4], b2f[2][4];
#pragma unroll
        for (int nf = 0; nf < 2; ++nf) {
            int n = w * 32 + nf * 16 + lr;
#pragma unroll
            for (int kk = 0; kk < 4; ++kk) {
                b1f[nf][kk] = *(const bf8*)&W1[(size_t)n * DIM + kk * 32 + q * 8];
                b2f[nf][kk] = *(const bf8*)&W2[(size_t)n * DIM + kk * 32 + q * 8];
            }
        }
        // x tile: h=0 from xb; else normalize previous out (red[0]) with smn/srv
#pragma unroll
        for (int i = 0; i < 2; ++i) {
            int idx = t + i * 256;
            int row = idx >> 4, c = (idx & 15) * 8;
            if (h == 0) {
                *(i32x4*)&lx[row][c] = *(const i32x4*)&xb[(size_t)(b * 32 + row) * DIM + c];
            } else {
                bf8 pk;
#pragma unroll
                for (int j = 0; j < 8; ++j) {
                    float v = red[0][row][c + j];
                    pk[j] = f2bf(fmaxf((v - smn[c + j]) * srv[c + j], 0.f));
                }
                *(bf8*)&lx[row][c] = pk;
            }
        }
        __syncthreads();
        // score -> coeff (all 256 threads: 32 rows x 8 segs)
        {
            int row = t >> 3, seg = t & 7;
            float id = idL[row];
            float s = 0.f;
#pragma unroll
            for (int j = 0; j < 16; ++j) {
                int c3 = seg * 16 + j;
                s += bf2f(lx[row][c3]) * sv1[c3] + bf2f(lp[row][c3]) * (sv2[c3] * id);
            }
            s += __shfl_xor(s, 1); s += __shfl_xor(s, 2); s += __shfl_xor(s, 4);
            if (seg == 0) {
                float sc = s + c1 + rsL[row] * c2 * id;
                sc = sc > 0.f ? sc : 0.2f * sc;
                coL[row] = 1.f / (1.f + __expf(-sc));
            }
        }
        // GEMM: wave w covers cols [w*32, w*32+32)
        f32x4 a1[2][2] = {{{0.f,0.f,0.f,0.f},{0.f,0.f,0.f,0.f}},{{0.f,0.f,0.f,0.f},{0.f,0.f,0.f,0.f}}};
        f32x4 a2[2][2] = {{{0.f,0.f,0.f,0.f},{0.f,0.f,0.f,0.f}},{{0.f,0.f,0.f,0.f},{0.f,0.f,0.f,0.f}}};
#pragma unroll
        for (int kk = 0; kk < 4; ++kk) {
#pragma unroll
            for (int rt = 0; rt < 2; ++rt) {
                bf8 xa = *(bf8*)&lx[rt * 16 + lr][kk * 32 + q * 8];
                bf8 pa = *(bf8*)&lp[rt * 16 + lr][kk * 32 + q * 8];
#pragma unroll
                for (int nf = 0; nf < 2; ++nf) {
                    a1[rt][nf] = __builtin_amdgcn_mfma_f32_16x16x32_bf16(xa, b1f[nf][kk], a1[rt][nf], 0, 0, 0);
                    a2[rt][nf] = __builtin_amdgcn_mfma_f32_16x16x32_bf16(pa, b2f[nf][kk], a2[rt][nf], 0, 0, 0);
                }
            }
        }
        __syncthreads();   // coL visible; lx/red reads complete before red overwrite
        // epilogue: raw out values into red[0], column min/max atomics
#pragma unroll
        for (int nf = 0; nf < 2; ++nf) {
            int col = w * 32 + nf * 16 + lr;
            float u1v = u1g[h * 128 + col], u2v = u2g[h * 128 + col];
            float mnv = 1e30f, mxv = -1e30f;
#pragma unroll
            for (int rt = 0; rt < 2; ++rt) {
#pragma unroll
                for (int r = 0; r < 4; ++r) {
                    int row = rt * 16 + q * 4 + r;
                    float cf = coL[row] * idL[row];
                    float v = a1[rt][nf][r] + cf * a2[rt][nf][r] + u1v + rsL[row] * cf * u2v;
                    red[0][row][col] = v;
                    mnv = fminf(mnv, v); mxv = fmaxf(mxv, v);
                }
            }
            mnv = fminf(mnv, __shfl_xor(mnv, 16)); mnv = fminf(mnv, __shfl_xor(mnv, 32));
            mxv = fmaxf(mxv, __shfl_xor(mxv, 16)); mxv = fmaxf(mxv, __shfl_xor(mxv, 32));
            if (l < 16) {
                atomicMin(&amin[h * 128 + col], fkey(mnv));
                atomicMax(&amax[h * 128 + col], fkey(mxv));
            }
        }
        grid.sync();
        if (t < 128) {
            float mn = fdec(amin[h * 128 + t]);
            smn[t] = mn;
            srv[t] = 1.f / (fdec(amax[h * 128 + t]) - mn + 1e-8f);
        }
        __syncthreads();
    }
    // ---- final normalize + relu -> d_out (coalesced) ----
#pragma unroll
    for (int i = 0; i < 4; ++i) {
        int idx = t + i * 256;
        int row = idx >> 5, c4 = (idx & 31) * 4;
        f32x4 v;
#pragma unroll
        for (int j = 0; j < 4; ++j)
            v[j] = fmaxf((red[0][row][c4 + j] - smn[c4 + j]) * srv[c4 + j], 0.f);
        *(f32x4*)&dout[(size_t)(b * 32 + row) * DIM + c4] = v;
    }
}

extern "C" void kernel_launch(void* const* d_in, const int* in_sizes, int n_in,
                              void* d_out, int out_size, void* d_ws, size_t ws_size,
                              hipStream_t stream) {
    const float* nodef = (const float*)d_in[0];
    const float* inc   = (const float*)d_in[1];
    const float* ef    = (const float*)d_in[2];
    const float* Wn    = (const float*)d_in[3];
    const float* bn    = (const float*)d_in[4];
    const float* We    = (const float*)d_in[5];
    const float* be    = (const float*)d_in[6];
    const float* Wa    = (const float*)d_in[7];
    const float* ba    = (const float*)d_in[8];
    const float* Wo    = (const float*)d_in[9];
    const float* bo    = (const float*)d_in[10];

    char* ws = (char*)d_ws;
    short*    xb   = (short*)(ws);                  // 2 MB
    short*    efB  = (short*)(ws + 2097152);        // 1 MB (swizzled)
    short*    incB = (short*)(ws + 3145728);        // 64 MB (swizzled)
    short*    A1T  = (short*)(ws + 70254592);       // 128 KB
    short*    A2T  = (short*)(ws + 70385664);       // 128 KB
    float*    rs   = (float*)(ws + 70516736);       // 32 KB
    float*    idg  = (float*)(ws + 70549504);       // 32 KB
    float*    v1   = (float*)(ws + 70582272);
    float*    v2   = (float*)(ws + 70584320);
    float*    u1   = (float*)(ws + 70586368);
    float*    u2   = (float*)(ws + 70588416);
    float*    cc   = (float*)(ws + 70590464);
    unsigned* amin = (unsigned*)(ws + 70592512);    // 4x128
    unsigned* amax = (unsigned*)(ws + 70594560);    // 4x128
    float*    dout = (float*)d_out;

    hipLaunchKernelGGL(k_init, dim3(512), dim3(256), 0, stream,
                       inc, incB, ef, efB, nodef, xb, Wn, We, Wo, Wa, bn, be, ba, bo,
                       A1T, A2T, v1, v2, u1, u2, cc, rs, idg, amin, amax);

    void* args[] = { (void*)&incB, (void*)&efB, (void*)&xb, (void*)&A1T, (void*)&A2T,
                     (void*)&v1, (void*)&v2, (void*)&u1, (void*)&u2, (void*)&cc,
                     (void*)&rs, (void*)&idg, (void*)&amin, (void*)&amax, (void*)&dout };
    hipLaunchCooperativeKernel((const void*)k_mega, dim3(256), dim3(256), args, 0, stream);
}

// Round 7
// 349.500 us; speedup vs baseline: 1.1737x; 1.1737x over previous
//
#include <hip/hip_runtime.h>
#include <hip/hip_bf16.h>
#include <stdint.h>
#include <math.h>

#define NODES 8192
#define EDGES 4096
#define DIM   128
#define HID   256
#define NHEADS 4

using bf8   = __attribute__((ext_vector_type(8))) short;
using f32x4 = __attribute__((ext_vector_type(4))) float;
using i32x4 = __attribute__((ext_vector_type(4))) int;
using s16x4 = __attribute__((ext_vector_type(4))) short;

__device__ __forceinline__ short f2bf(float f) {
    uint32_t u = __float_as_uint(f);
    u += 0x7fffu + ((u >> 16) & 1u);   // RNE
    return (short)(u >> 16);
}
__device__ __forceinline__ float bf2f(short s) {
    return __uint_as_float(((uint32_t)(unsigned short)s) << 16);
}
// order-preserving float<->uint key for atomic min/max
__device__ __forceinline__ unsigned fkey(float f) {
    unsigned u = __float_as_uint(f);
    return (u & 0x80000000u) ? ~u : (u | 0x80000000u);
}
__device__ __forceinline__ float fdec(unsigned k) {
    unsigned u = (k & 0x80000000u) ? (k & 0x7fffffffu) : ~k;
    return __uint_as_float(u);
}

// Fragment-swizzled operand layout for 16x16x32 MFMA:
//   buf[(tile16 * 128 + chunk32) * 512 + lane * 8 .. +7]  (shorts)
// lane = q*16 + r holds elems [row/col = tile*16 + r][k = chunk*32 + q*8 + j].

// ============ k_init: incidence->swizzled bf16 (register path, no barriers) + rowsum,
//              ef->swizzled bf16, x->bf16, fused weights/vectors, amin/amax init ============
__global__ __launch_bounds__(256) void k_init(
        const float* __restrict__ inc, short* __restrict__ incB,
        const float* __restrict__ ef, short* __restrict__ efB,
        const float* __restrict__ xf, short* __restrict__ xb,
        const float* __restrict__ Wn, const float* __restrict__ We, const float* __restrict__ Wo,
        const float* __restrict__ Wa, const float* __restrict__ bn, const float* __restrict__ be,
        const float* __restrict__ ba, const float* __restrict__ bo,
        short* __restrict__ A1T, short* __restrict__ A2T,
        float* __restrict__ v1, float* __restrict__ v2,
        float* __restrict__ u1, float* __restrict__ u2, float* __restrict__ cc,
        float* __restrict__ rs, float* __restrict__ idg,
        unsigned* __restrict__ amin, unsigned* __restrict__ amax) {
    __shared__ __align__(16) char smem[17408];
    int b = blockIdx.x, t = threadIdx.x;

    // ---- (1) blocks 0..127: build swizzled efB from ef [4096][128] ----
    if (b < 128) {
        float (*lb)[132] = (float(*)[132])smem;
        int k0 = b * 32;
#pragma unroll
        for (int i = 0; i < 4; ++i) {
            int idx4 = t + i * 256;
            int kk = idx4 >> 5, nq = idx4 & 31;
            f32x4 v = *(const f32x4*)&ef[(size_t)(k0 + kk) * DIM + nq * 4];
            lb[kk][nq * 4 + 0] = v[0]; lb[kk][nq * 4 + 1] = v[1];
            lb[kk][nq * 4 + 2] = v[2]; lb[kk][nq * 4 + 3] = v[3];
        }
        __syncthreads();
#pragma unroll
        for (int i = 0; i < 2; ++i) {
            int o = t + i * 256;
            int nt = o >> 6, lane = o & 63, nr = lane & 15, qq = lane >> 4;
            bf8 pk;
#pragma unroll
            for (int j = 0; j < 8; ++j) pk[j] = f2bf(lb[qq * 8 + j][nt * 16 + nr]);
            *(bf8*)&efB[((size_t)nt * 128 + b) * 512 + lane * 8] = pk;
        }
        __syncthreads();
    }

    // ---- (2) all blocks: incidence 16-row tile b -> swizzled bf16 + rowsum; pure register path ----
    {
        const int row = t >> 4, koff = t & 15;
        const float* ip = inc + (size_t)(b * 16 + row) * EDGES + koff * 8;
        short* ob = incB + (size_t)b * 65536;   // tile b: 128 chunks * 512 shorts
        const int obase = (koff >> 2) * 512 + ((koff & 3) * 16 + row) * 8;
        float rsacc = 0.f;
#pragma unroll 4
        for (int sc = 0; sc < 32; ++sc) {
            f32x4 v0 = *(const f32x4*)(ip + sc * 128);
            f32x4 v1v = *(const f32x4*)(ip + sc * 128 + 4);
            bf8 pk;
#pragma unroll
            for (int j = 0; j < 4; ++j) {
                pk[j] = f2bf(v0[j]); pk[4 + j] = f2bf(v1v[j]);
                rsacc += v0[j] + v1v[j];
            }
            *(bf8*)&ob[(size_t)(sc * 4) * 512 + obase] = pk;
        }
        rsacc += __shfl_xor(rsacc, 1); rsacc += __shfl_xor(rsacc, 2);
        rsacc += __shfl_xor(rsacc, 4); rsacc += __shfl_xor(rsacc, 8);
        if (koff == 0) {
            rs[b * 16 + row] = rsacc;
            idg[b * 16 + row] = 1.f / (rsacc + 1e-8f);
        }
    }

    // ---- (3) node_features f32 -> bf16 ----
#pragma unroll
    for (int i = 0; i < 2; ++i) {
        int idx = b * 256 + t + i * 131072;
        f32x4 v = *((const f32x4*)xf + idx);
        s16x4 o;
#pragma unroll
        for (int j = 0; j < 4; ++j) o[j] = f2bf(v[j]);
        *((s16x4*)xb + idx) = o;
    }
    // ---- (4) amin/amax init (4 heads x 128) ----
    if (b == 511) {
#pragma unroll
        for (int i = 0; i < 2; ++i) {
            int u = t + i * 256;
            amin[u] = 0xFFFFFFFFu;
            amax[u] = 0u;
        }
    }

    // ---- (5) blocks 128..383: fused weights A1T=(Wn@Wo)^T, A2T=(We@Wo)^T ----
    if (b >= 128 && b < 384) {
        float (*lw)[128][17] = (float(*)[128][17])smem;
        int bb = b - 128;
        int h = bb >> 6, jj = bb & 63;
        int mat = t >> 7, k = t & 127;
        const float* WoH = Wo + (size_t)h * HID * DIM;
        float acc0 = 0.f, acc1 = 0.f;
        for (int mc = 0; mc < 16; ++mc) {
            __syncthreads();
#pragma unroll
            for (int i = 0; i < 4; ++i) {
                int u = t + i * 256;
                int m_ = u >> 9, kk2 = (u >> 2) & 127, qd = u & 3;
                const float* src = (m_ ? We : Wn) + (size_t)h * DIM * HID + (size_t)kk2 * HID + mc * 16 + qd * 4;
                f32x4 val = *(const f32x4*)src;
#pragma unroll
                for (int j2 = 0; j2 < 4; ++j2) lw[m_][kk2][qd * 4 + j2] = val[j2];
            }
            __syncthreads();
#pragma unroll
            for (int mm = 0; mm < 16; ++mm) {
                float a = lw[mat][k][mm];
                int m = mc * 16 + mm;
                acc0 += a * WoH[(size_t)m * DIM + jj];
                acc1 += a * WoH[(size_t)m * DIM + jj + 64];
            }
        }
        short* dst = mat ? A2T : A1T;
        dst[(size_t)h * DIM * DIM + (size_t)jj * DIM + k] = f2bf(acc0);
        dst[(size_t)h * DIM * DIM + (size_t)(jj + 64) * DIM + k] = f2bf(acc1);
    } else if (b >= 384 && b < 388) {
        // ---- (6) fused vectors for head h ----
        float (*lw)[128][17] = (float(*)[128][17])smem;
        int h = b - 384;
        int mat = t >> 7, k = t & 127;
        const float* wa = Wa + (size_t)h * HID;
        float acc = 0.f;
        for (int mc = 0; mc < 16; ++mc) {
            __syncthreads();
#pragma unroll
            for (int i = 0; i < 4; ++i) {
                int u = t + i * 256;
                int m_ = u >> 9, kk2 = (u >> 2) & 127, qd = u & 3;
                const float* src = (m_ ? We : Wn) + (size_t)h * DIM * HID + (size_t)kk2 * HID + mc * 16 + qd * 4;
                f32x4 val = *(const f32x4*)src;
#pragma unroll
                for (int j2 = 0; j2 < 4; ++j2) lw[m_][kk2][qd * 4 + j2] = val[j2];
            }
            __syncthreads();
#pragma unroll
            for (int mm = 0; mm < 16; ++mm) acc += lw[mat][k][mm] * wa[mc * 16 + mm];
        }
        (mat ? v2 : v1)[h * DIM + k] = acc;
        const float* bias = (mat ? be : bn) + (size_t)h * HID;
        const float* WoH = Wo + (size_t)h * HID * DIM;
        float ua = 0.f;
        for (int m = 0; m < HID; ++m) ua += bias[m] * WoH[(size_t)m * DIM + k];
        if (mat) u2[h * DIM + k] = ua;
        else     u1[h * DIM + k] = ua + bo[h * DIM + k];
        if (t < 64) {
            float c = 0.f;
#pragma unroll
            for (int j = 0; j < 4; ++j) { int m = t + j * 64; c += bn[(size_t)h * HID + m] * wa[m]; }
#pragma unroll
            for (int off = 1; off < 64; off <<= 1) c += __shfl_xor(c, off);
            if (t == 0) cc[h * 2 + 0] = c + ba[h];
        } else if (t < 128) {
            int l2 = t - 64;
            float c = 0.f;
#pragma unroll
            for (int j = 0; j < 4; ++j) { int m = l2 + j * 64; c += be[(size_t)h * HID + m] * wa[m]; }
#pragma unroll
            for (int off = 1; off < 64; off <<= 1) c += __shfl_xor(c, off);
            if (l2 == 0) cc[h * 2 + 1] = c;
        }
    }
}

// ============ k_pgemm: P = incidence @ ef, full-K, M-tile 16, 512 blocks (2/CU) ============
// Wave w owns K chunks [w*32, w*32+32); cross-wave reduce in LDS; writes Pbf directly.
__global__ __launch_bounds__(256) void k_pgemm(const short* __restrict__ incB, const short* __restrict__ efB,
        short* __restrict__ Pbf) {
    __shared__ float red[2][16][132];
    const int t = threadIdx.x, m = blockIdx.x;
    const int w = t >> 6, l = t & 63, q = l >> 4, lr = l & 15;
    const short* ap = incB + ((size_t)m * 128 + w * 32) * 512 + l * 8;
    const short* bp = efB + ((size_t)w * 32) * 512 + l * 8;
    f32x4 acc[8];
#pragma unroll
    for (int cb = 0; cb < 8; ++cb) acc[cb] = (f32x4){0.f, 0.f, 0.f, 0.f};
    bf8 aA, bA[8], aB, bB[8];
    aA = *(const bf8*)ap;
#pragma unroll
    for (int cb = 0; cb < 8; ++cb) bA[cb] = *(const bf8*)(bp + (size_t)cb * 65536);
    for (int s = 0; s < 32; s += 2) {
        // prefetch s+1
        aB = *(const bf8*)(ap + (s + 1) * 512);
#pragma unroll
        for (int cb = 0; cb < 8; ++cb) bB[cb] = *(const bf8*)(bp + (size_t)cb * 65536 + (s + 1) * 512);
#pragma unroll
        for (int cb = 0; cb < 8; ++cb)
            acc[cb] = __builtin_amdgcn_mfma_f32_16x16x32_bf16(aA, bA[cb], acc[cb], 0, 0, 0);
        if (s + 2 < 32) {
            aA = *(const bf8*)(ap + (s + 2) * 512);
#pragma unroll
            for (int cb = 0; cb < 8; ++cb) bA[cb] = *(const bf8*)(bp + (size_t)cb * 65536 + (s + 2) * 512);
        }
#pragma unroll
        for (int cb = 0; cb < 8; ++cb)
            acc[cb] = __builtin_amdgcn_mfma_f32_16x16x32_bf16(aB, bB[cb], acc[cb], 0, 0, 0);
    }
    // cross-wave reduce: w0->red[0], w1->red[1]; then w2 += red[0], w3 += red[1]
    if (w < 2) {
#pragma unroll
        for (int cb = 0; cb < 8; ++cb)
#pragma unroll
            for (int r = 0; r < 4; ++r)
                red[w][q * 4 + r][cb * 16 + lr] = acc[cb][r];
    }
    __syncthreads();
    if (w >= 2) {
#pragma unroll
        for (int cb = 0; cb < 8; ++cb)
#pragma unroll
            for (int r = 0; r < 4; ++r)
                red[w - 2][q * 4 + r][cb * 16 + lr] += acc[cb][r];
    }
    __syncthreads();
    {
        int row = t >> 4, c = (t & 15) * 8;
        bf8 pk;
#pragma unroll
        for (int j = 0; j < 8; ++j) pk[j] = f2bf(red[0][row][c + j] + red[1][row][c + j]);
        *(bf8*)&Pbf[(size_t)(m * 16 + row) * DIM + c] = pk;
    }
}

// ============ k_out: per-head fused normalize-in + score + GEMM + atomic minmax ============
__global__ __launch_bounds__(256) void k_out(
        const short* __restrict__ xb,      // head 0 input (bf16) or nullptr
        const float* xf,                   // heads>=1: prev outp f32 (aliases outw)
        const unsigned* __restrict__ aminP, const unsigned* __restrict__ amaxP,
        const short* __restrict__ Pbf, const float* __restrict__ rs, const float* __restrict__ idg,
        const short* __restrict__ W1, const short* __restrict__ W2,
        const float* __restrict__ v1, const float* __restrict__ v2,
        const float* __restrict__ cc, const float* __restrict__ u1, const float* __restrict__ u2,
        unsigned* __restrict__ aminC, unsigned* __restrict__ amaxC,
        float* outw) {
    __shared__ short lx[16][136];
    __shared__ short lp[16][136];
    __shared__ float sv1[128], sv2[128], rsL[16], idL[16], coL[16];
    int t = threadIdx.x, m0 = blockIdx.x * 16;
    int w = t >> 6, l = t & 63, q = l >> 4, lr = l & 15;
    bf8 b1[2][4], b2[2][4];
#pragma unroll
    for (int nf = 0; nf < 2; ++nf) {
        int n = w * 32 + nf * 16 + lr;
#pragma unroll
        for (int kk = 0; kk < 4; ++kk) {
            b1[nf][kk] = *(const bf8*)&W1[(size_t)n * DIM + kk * 32 + q * 8];
            b2[nf][kk] = *(const bf8*)&W2[(size_t)n * DIM + kk * 32 + q * 8];
        }
    }
    {
        int row = t >> 4, c = (t & 15) * 8;
        if (xb) {
            *(i32x4*)&lx[row][c] = *(const i32x4*)&xb[(size_t)(m0 + row) * DIM + c];
        } else {
            f32x4 x0 = *(const f32x4*)&xf[(size_t)(m0 + row) * DIM + c];
            f32x4 x1 = *(const f32x4*)&xf[(size_t)(m0 + row) * DIM + c + 4];
            bf8 pk;
#pragma unroll
            for (int j = 0; j < 8; ++j) {
                float mn = fdec(aminP[c + j]);
                float rv = 1.f / (fdec(amaxP[c + j]) - mn + 1e-8f);
                float xv = (j < 4) ? x0[j] : x1[j - 4];
                pk[j] = f2bf(fmaxf((xv - mn) * rv, 0.f));
            }
            *(bf8*)&lx[row][c] = pk;
        }
        *(i32x4*)&lp[row][c] = *(const i32x4*)&Pbf[(size_t)(m0 + row) * DIM + c];
    }
    if (t < 128) { sv1[t] = v1[t]; sv2[t] = v2[t]; }
    if (t < 16) { rsL[t] = rs[m0 + t]; idL[t] = idg[m0 + t]; }
    __syncthreads();
    if (t < 128) {
        int row = t >> 3, seg = t & 7;
        float id = idL[row];
        float s = 0.f;
#pragma unroll
        for (int j = 0; j < 16; ++j) {
            int c3 = seg * 16 + j;
            s += bf2f(lx[row][c3]) * sv1[c3] + bf2f(lp[row][c3]) * (sv2[c3] * id);
        }
        s += __shfl_xor(s, 1); s += __shfl_xor(s, 2); s += __shfl_xor(s, 4);
        if (seg == 0) {
            float sc = s + cc[0] + rsL[row] * cc[1] * id;
            sc = sc > 0.f ? sc : 0.2f * sc;
            coL[row] = 1.f / (1.f + __expf(-sc));
        }
    }
    f32x4 a1[2] = {{0.f, 0.f, 0.f, 0.f}, {0.f, 0.f, 0.f, 0.f}};
    f32x4 a2[2] = {{0.f, 0.f, 0.f, 0.f}, {0.f, 0.f, 0.f, 0.f}};
#pragma unroll
    for (int kk = 0; kk < 4; ++kk) {
        bf8 xa = *(bf8*)&lx[lr][kk * 32 + q * 8];
        bf8 pa = *(bf8*)&lp[lr][kk * 32 + q * 8];
#pragma unroll
        for (int nf = 0; nf < 2; ++nf) {
            a1[nf] = __builtin_amdgcn_mfma_f32_16x16x32_bf16(xa, b1[nf][kk], a1[nf], 0, 0, 0);
            a2[nf] = __builtin_amdgcn_mfma_f32_16x16x32_bf16(pa, b2[nf][kk], a2[nf], 0, 0, 0);
        }
    }
    __syncthreads();   // coL visible
#pragma unroll
    for (int nf = 0; nf < 2; ++nf) {
        int col = w * 32 + nf * 16 + lr;
        float u1v = u1[col], u2v = u2[col];
        float mnv = 1e30f, mxv = -1e30f;
#pragma unroll
        for (int r = 0; r < 4; ++r) {
            int row = q * 4 + r;
            float cf = coL[row] * idL[row];
            float v = a1[nf][r] + cf * a2[nf][r] + u1v + rsL[row] * cf * u2v;
            outw[(size_t)(m0 + row) * DIM + col] = v;
            mnv = fminf(mnv, v); mxv = fmaxf(mxv, v);
        }
        mnv = fminf(mnv, __shfl_xor(mnv, 16)); mnv = fminf(mnv, __shfl_xor(mnv, 32));
        mxv = fmaxf(mxv, __shfl_xor(mxv, 16)); mxv = fmaxf(mxv, __shfl_xor(mxv, 32));
        if (l < 16) {
            atomicMin(&aminC[col], fkey(mnv));
            atomicMax(&amaxC[col], fkey(mxv));
        }
    }
}

// ============ k_fin: decode last head's minmax, normalize + relu -> d_out ============
__global__ __launch_bounds__(256) void k_fin(const float* __restrict__ outp,
        const unsigned* __restrict__ amin, const unsigned* __restrict__ amax,
        float* __restrict__ dst) {
    __shared__ float smn[128], srv[128];
    int t = threadIdx.x;
    if (t < 128) {
        float mn = fdec(amin[t]);
        smn[t] = mn;
        srv[t] = 1.f / (fdec(amax[t]) - mn + 1e-8f);
    }
    __syncthreads();
#pragma unroll
    for (int i = 0; i < 2; ++i) {
        int idx = blockIdx.x * 256 + t + i * 131072;
        f32x4 v = *((const f32x4*)outp + idx);
        int c0 = (idx & 31) * 4;
#pragma unroll
        for (int j = 0; j < 4; ++j) v[j] = fmaxf((v[j] - smn[c0 + j]) * srv[c0 + j], 0.f);
        *((f32x4*)dst + idx) = v;
    }
}

extern "C" void kernel_launch(void* const* d_in, const int* in_sizes, int n_in,
                              void* d_out, int out_size, void* d_ws, size_t ws_size,
                              hipStream_t stream) {
    const float* nodef = (const float*)d_in[0];
    const float* inc   = (const float*)d_in[1];
    const float* ef    = (const float*)d_in[2];
    const float* Wn    = (const float*)d_in[3];
    const float* bn    = (const float*)d_in[4];
    const float* We    = (const float*)d_in[5];
    const float* be    = (const float*)d_in[6];
    const float* Wa    = (const float*)d_in[7];
    const float* ba    = (const float*)d_in[8];
    const float* Wo    = (const float*)d_in[9];
    const float* bo    = (const float*)d_in[10];

    char* ws = (char*)d_ws;
    short*    xb   = (short*)(ws);                  // 2 MB
    short*    efB  = (short*)(ws + 2097152);        // 1 MB (swizzled)
    short*    incB = (short*)(ws + 3145728);        // 64 MB (swizzled)
    short*    Pbf  = (short*)(ws + 70254592);       // 2 MB
    float*    outp = (float*)(ws + 72351744);       // 4 MB
    short*    A1T  = (short*)(ws + 76546048);       // 128 KB
    short*    A2T  = (short*)(ws + 76677120);       // 128 KB
    float*    rs   = (float*)(ws + 76808192);       // 32 KB
    float*    idg  = (float*)(ws + 76840960);       // 32 KB
    float*    v1   = (float*)(ws + 76873728);
    float*    v2   = (float*)(ws + 76875776);
    float*    u1   = (float*)(ws + 76877824);
    float*    u2   = (float*)(ws + 76879872);
    float*    cc   = (float*)(ws + 76881920);
    unsigned* amin = (unsigned*)(ws + 76883968);    // 4x128
    unsigned* amax = (unsigned*)(ws + 76886016);    // 4x128

    hipLaunchKernelGGL(k_init, dim3(512), dim3(256), 0, stream,
                       inc, incB, ef, efB, nodef, xb, Wn, We, Wo, Wa, bn, be, ba, bo,
                       A1T, A2T, v1, v2, u1, u2, cc, rs, idg, amin, amax);
    hipLaunchKernelGGL(k_pgemm, dim3(512), dim3(256), 0, stream, incB, efB, Pbf);

    for (int h = 0; h < NHEADS; ++h) {
        hipLaunchKernelGGL(k_out, dim3(512), dim3(256), 0, stream,
                           (h == 0) ? xb : (const short*)nullptr,
                           (h == 0) ? (const float*)nullptr : outp,
                           (h == 0) ? (const unsigned*)nullptr : amin + (h - 1) * DIM,
                           (h == 0) ? (const unsigned*)nullptr : amax + (h - 1) * DIM,
                           Pbf, rs, idg,
                           A1T + (size_t)h * DIM * DIM, A2T + (size_t)h * DIM * DIM,
                           v1 + h * DIM, v2 + h * DIM, cc + h * 2,
                           u1 + h * DIM, u2 + h * DIM,
                           amin + h * DIM, amax + h * DIM, outp);
    }
    hipLaunchKernelGGL(k_fin, dim3(512), dim3(256), 0, stream, outp,
                       amin + 3 * DIM, amax + 3 * DIM, (float*)d_out);
}